// Round 2
// baseline (1007.656 us; speedup 1.0000x reference)
//
#include <hip/hip_runtime.h>

// Problem constants (fixed by setup_inputs)
constexpr int NPTS = 16384;
constexpr int KNB  = 9;
constexpr int CDIM = 16;
constexpr int HDIM = 32;
constexpr int G    = 128;          // bin grid is G x G
constexpr int GC   = G * G;        // 16384 cells
constexpr float FBIG = 3.0e38f;

// ---------------------------------------------------------------------------
// Register-resident top-9 (smallest d2). Slot arrays indexed only with
// compile-time constants -> stay in VGPRs. Replace-the-worst + max3 rescan.
// With ~50-100 candidates/point the push body cost is negligible.
// ---------------------------------------------------------------------------
struct TopK {
    float d[KNB];
    int   id[KNB];
    float dw;   // current worst (max) of the 9; == FBIG until 9 pushed

    __device__ __forceinline__ void init() {
#pragma unroll
        for (int s = 0; s < KNB; ++s) { d[s] = FBIG; id[s] = -1; }
        dw = FBIG;
    }

    __device__ __forceinline__ void push(float d2, int j) {
        if (d2 < dw) {
            bool done = false;
#pragma unroll
            for (int s = 0; s < KNB; ++s) {
                bool m = (!done) && (d[s] == dw);
                d[s]  = m ? d2 : d[s];
                id[s] = m ? j  : id[s];
                done  = done || m;
            }
            float m0 = fmaxf(fmaxf(d[0], d[1]), d[2]);
            float m1 = fmaxf(fmaxf(d[3], d[4]), d[5]);
            float m2 = fmaxf(fmaxf(d[6], d[7]), d[8]);
            dw = fmaxf(fmaxf(m0, m1), m2);
        }
    }
};

// ---------------------------------------------------------------------------
// Bounding box of x[:, :2] -> bounds = {minx, miny, maxx, maxy}
// ---------------------------------------------------------------------------
__global__ __launch_bounds__(1024) void bbox_kernel(const float* __restrict__ x,
                                                    float* __restrict__ bounds) {
    __shared__ float s0[1024], s1[1024], s2[1024], s3[1024];
    const int t = threadIdx.x;
    float mnx = FBIG, mny = FBIG, mxx = -FBIG, mxy = -FBIG;
    for (int i = t; i < NPTS; i += 1024) {
        const float px = x[i * CDIM + 0];
        const float py = x[i * CDIM + 1];
        mnx = fminf(mnx, px); mny = fminf(mny, py);
        mxx = fmaxf(mxx, px); mxy = fmaxf(mxy, py);
    }
    s0[t] = mnx; s1[t] = mny; s2[t] = mxx; s3[t] = mxy;
    __syncthreads();
    for (int off = 512; off > 0; off >>= 1) {
        if (t < off) {
            s0[t] = fminf(s0[t], s0[t + off]);
            s1[t] = fminf(s1[t], s1[t + off]);
            s2[t] = fmaxf(s2[t], s2[t + off]);
            s3[t] = fmaxf(s3[t], s3[t + off]);
        }
        __syncthreads();
    }
    if (t == 0) {
        bounds[0] = s0[0]; bounds[1] = s1[0];
        bounds[2] = s2[0]; bounds[3] = s3[0];
    }
}

__device__ __forceinline__ int cell_coord(float p, float mn, float invw) {
    int c = (int)((p - mn) * invw);
    return min(G - 1, max(0, c));
}

// ---------------------------------------------------------------------------
// Count points per cell; remember each point's cell.
// ---------------------------------------------------------------------------
__global__ __launch_bounds__(256) void bin_count(const float* __restrict__ x,
                                                 const float* __restrict__ bounds,
                                                 int* __restrict__ cellCount,
                                                 int* __restrict__ cellOf) {
    const int i = blockIdx.x * 256 + threadIdx.x;
    const float invwx = (float)G / (bounds[2] - bounds[0]);
    const float invwy = (float)G / (bounds[3] - bounds[1]);
    const float px = x[i * CDIM + 0];
    const float py = x[i * CDIM + 1];
    const int cx = cell_coord(px, bounds[0], invwx);
    const int cy = cell_coord(py, bounds[1], invwy);
    const int c = cy * G + cx;
    cellOf[i] = c;
    atomicAdd(&cellCount[c], 1);
}

// ---------------------------------------------------------------------------
// Exclusive prefix sum over GC=16384 counts, single block of 1024 (16/thread
// serial + LDS Hillis-Steele). Writes cellStart[GC+1] and cursor (= copy).
// ---------------------------------------------------------------------------
__global__ __launch_bounds__(1024) void scan_kernel(const int* __restrict__ cellCount,
                                                    int* __restrict__ cellStart,
                                                    int* __restrict__ cursor) {
    __shared__ int S[1024];
    const int t = threadIdx.x;
    const int base = t * 16;
    int loc[16];
    int sum = 0;
#pragma unroll
    for (int k = 0; k < 16; ++k) { loc[k] = sum; sum += cellCount[base + k]; }
    S[t] = sum;
    __syncthreads();
    for (int off = 1; off < 1024; off <<= 1) {
        const int v = (t >= off) ? S[t - off] : 0;
        __syncthreads();
        S[t] += v;
        __syncthreads();
    }
    const int excl = S[t] - sum;
#pragma unroll
    for (int k = 0; k < 16; ++k) {
        const int v = excl + loc[k];
        cellStart[base + k] = v;
        cursor[base + k] = v;
    }
    if (t == 1023) cellStart[GC] = NPTS;
}

// ---------------------------------------------------------------------------
// Scatter points into binned order: coords, original index, and the full
// 16-ch feature row (so layer-1 gathers and the final residual read are in
// binned order -> spatially local).
// ---------------------------------------------------------------------------
__global__ __launch_bounds__(256) void scatter_kernel(const float* __restrict__ x,
                                                      const int* __restrict__ cellOf,
                                                      int* __restrict__ cursor,
                                                      float* __restrict__ bx,
                                                      float* __restrict__ by,
                                                      int* __restrict__ bid,
                                                      float* __restrict__ xb) {
    const int i = blockIdx.x * 256 + threadIdx.x;
    const int c = cellOf[i];
    const int pos = atomicAdd(&cursor[c], 1);
    const float4* src = reinterpret_cast<const float4*>(x + (size_t)i * CDIM);
    float4* dst = reinterpret_cast<float4*>(xb + (size_t)pos * CDIM);
    const float4 v0 = src[0];
    dst[0] = v0; dst[1] = src[1]; dst[2] = src[2]; dst[3] = src[3];
    bx[pos] = v0.x;
    by[pos] = v0.y;
    bid[pos] = i;
}

// ---------------------------------------------------------------------------
// Exact kNN by expanding-ring search over the cell grid. Thread per binned
// point (wave lanes are spatially adjacent -> coherent cell loops, L1 hits).
// Stop when the 9th-best d2 <= squared distance to the uncovered region
// (clipped grid sides count as +inf; negative fp slop clamped to 0 so we can
// only over-expand, never stop early). nb[] holds BINNED neighbor positions.
// ---------------------------------------------------------------------------
__global__ __launch_bounds__(256) void knn_search(const float* __restrict__ bx,
                                                  const float* __restrict__ by,
                                                  const int* __restrict__ cellStart,
                                                  const float* __restrict__ bounds,
                                                  int* __restrict__ nb) {
    const int p = blockIdx.x * 256 + threadIdx.x;
    const float qx = bx[p];
    const float qy = by[p];
    const float minx = bounds[0], miny = bounds[1];
    const float wx = (bounds[2] - bounds[0]) * (1.0f / G);
    const float wy = (bounds[3] - bounds[1]) * (1.0f / G);
    const float invwx = (float)G / (bounds[2] - bounds[0]);
    const float invwy = (float)G / (bounds[3] - bounds[1]);
    const int cx = cell_coord(qx, minx, invwx);
    const int cy = cell_coord(qy, miny, invwy);

    TopK tk; tk.init();

    auto row_span = [&](int y, int x0, int x1) {
        if (y < 0 || y >= G) return;
        x0 = max(x0, 0); x1 = min(x1, G - 1);
        if (x0 > x1) return;
        const int s = cellStart[y * G + x0];
        const int e = cellStart[y * G + x1 + 1];
        for (int i = s; i < e; ++i) {
            const float dx = qx - bx[i];
            const float dy = qy - by[i];
            tk.push(fmaf(dx, dx, dy * dy), i);
        }
    };
    auto one_cell = [&](int y, int xx) {
        if (y < 0 || y >= G || xx < 0 || xx >= G) return;
        const int c = y * G + xx;
        const int s = cellStart[c];
        const int e = cellStart[c + 1];
        for (int i = s; i < e; ++i) {
            const float dx = qx - bx[i];
            const float dy = qy - by[i];
            tk.push(fmaf(dx, dx, dy * dy), i);
        }
    };

    // initial 3x3 block (covers r=1)
    row_span(cy - 1, cx - 1, cx + 1);
    row_span(cy,     cx - 1, cx + 1);
    row_span(cy + 1, cx - 1, cx + 1);

    int r = 1;
    while (true) {
        // distance from q to the uncovered region outside the (2r+1)^2 block
        const float dl = (cx - r >= 0) ? fmaxf(qx - (minx + (float)(cx - r) * wx), 0.0f) : FBIG;
        const float dr = (cx + r <  G) ? fmaxf((minx + (float)(cx + r + 1) * wx) - qx, 0.0f) : FBIG;
        const float db = (cy - r >= 0) ? fmaxf(qy - (miny + (float)(cy - r) * wy), 0.0f) : FBIG;
        const float dt = (cy + r <  G) ? fmaxf((miny + (float)(cy + r + 1) * wy) - qy, 0.0f) : FBIG;
        const float dmin = fminf(fminf(dl, dr), fminf(db, dt));
        if (tk.dw < FBIG && tk.dw <= dmin * dmin) break;
        ++r;
        if (r >= G) break;
        row_span(cy - r, cx - r, cx + r);
        row_span(cy + r, cx - r, cx + r);
        for (int y = cy - r + 1; y <= cy + r - 1; ++y) {
            one_cell(y, cx - r);
            one_cell(y, cx + r);
        }
    }

#pragma unroll
    for (int s = 0; s < KNB; ++s) nb[p * KNB + s] = tk.id[s];
}

// ---------------------------------------------------------------------------
// One GCN layer in BINNED order: agg = mean_k(hin[nb[p,k]]); out = agg @ W;
// optional ReLU; FINAL fuses residual (xb) and scatters to original order
// via bid. W broadcast from LDS (wave-uniform reads).
// ---------------------------------------------------------------------------
template <int CIN, int COUT, bool RELU, bool FINAL>
__global__ __launch_bounds__(256) void gcn_layer(const float* __restrict__ hin,
                                                 const int* __restrict__ nb,
                                                 const float* __restrict__ W,
                                                 const float* __restrict__ xb,
                                                 const int* __restrict__ bid,
                                                 float* __restrict__ hout) {
    __shared__ float Ws[CIN * COUT];
    for (int t = threadIdx.x; t < CIN * COUT; t += 256) Ws[t] = W[t];
    __syncthreads();

    const int n = blockIdx.x * 256 + threadIdx.x;

    float agg[CIN];
#pragma unroll
    for (int c = 0; c < CIN; ++c) agg[c] = 0.0f;

#pragma unroll
    for (int k = 0; k < KNB; ++k) {
        const int j = nb[n * KNB + k];
        const float4* r = reinterpret_cast<const float4*>(hin + (size_t)j * CIN);
#pragma unroll
        for (int c4 = 0; c4 < CIN / 4; ++c4) {
            const float4 v = r[c4];
            agg[4 * c4 + 0] += v.x;
            agg[4 * c4 + 1] += v.y;
            agg[4 * c4 + 2] += v.z;
            agg[4 * c4 + 3] += v.w;
        }
    }
    constexpr float inv = 1.0f / 9.0f;
#pragma unroll
    for (int c = 0; c < CIN; ++c) agg[c] *= inv;

    const int outrow = FINAL ? bid[n] : n;
#pragma unroll
    for (int o = 0; o < COUT; ++o) {
        float acc = 0.0f;
#pragma unroll
        for (int c = 0; c < CIN; ++c) acc = fmaf(agg[c], Ws[c * COUT + o], acc);
        if (RELU)  acc = fmaxf(acc, 0.0f);
        if (FINAL) acc = xb[n * COUT + o] + 1e-4f * acc;
        hout[outrow * COUT + o] = acc;
    }
}

// ---------------------------------------------------------------------------
// Launch: 2 fixed steps. Per step: bbox -> count -> scan -> scatter ->
// ring-kNN -> 4 GCN layers (final scatters back to original order).
// ---------------------------------------------------------------------------
extern "C" void kernel_launch(void* const* d_in, const int* in_sizes, int n_in,
                              void* d_out, int out_size, void* d_ws, size_t ws_size,
                              hipStream_t stream) {
    const float* seed = (const float*)d_in[0];
    const float* W1   = (const float*)d_in[1];
    const float* W2   = (const float*)d_in[2];
    const float* W3   = (const float*)d_in[3];
    const float* W4   = (const float*)d_in[4];
    float* out = (float*)d_out;

    char* ws = (char*)d_ws;
    size_t off = 0;
    auto alloc = [&](size_t bytes) -> void* {
        void* p = ws + off;
        off += (bytes + 255) & ~(size_t)255;
        return p;
    };
    float* bounds    = (float*)alloc(4 * sizeof(float));
    int*   cellCount = (int*)  alloc(GC * sizeof(int));
    int*   cellStart = (int*)  alloc((GC + 1) * sizeof(int));
    int*   cursor    = (int*)  alloc(GC * sizeof(int));
    int*   cellOf    = (int*)  alloc(NPTS * sizeof(int));
    float* bx        = (float*)alloc(NPTS * sizeof(float));
    float* by        = (float*)alloc(NPTS * sizeof(float));
    int*   bid       = (int*)  alloc(NPTS * sizeof(int));
    float* xb        = (float*)alloc((size_t)NPTS * CDIM * sizeof(float));
    int*   nb        = (int*)  alloc((size_t)NPTS * KNB * sizeof(int));
    float* hA        = (float*)alloc((size_t)NPTS * HDIM * sizeof(float));
    float* hB        = (float*)alloc((size_t)NPTS * HDIM * sizeof(float));
    float* x1        = (float*)alloc((size_t)NPTS * CDIM * sizeof(float));

    constexpr int NB = NPTS / 256;   // 64 blocks of 256

    for (int step = 0; step < 2; ++step) {
        const float* xin  = (step == 0) ? seed : x1;
        float*       xout = (step == 0) ? x1   : out;

        hipMemsetAsync(cellCount, 0, GC * sizeof(int), stream);
        bbox_kernel   <<<1, 1024, 0, stream>>>(xin, bounds);
        bin_count     <<<NB, 256, 0, stream>>>(xin, bounds, cellCount, cellOf);
        scan_kernel   <<<1, 1024, 0, stream>>>(cellCount, cellStart, cursor);
        scatter_kernel<<<NB, 256, 0, stream>>>(xin, cellOf, cursor, bx, by, bid, xb);
        knn_search    <<<NB, 256, 0, stream>>>(bx, by, cellStart, bounds, nb);

        gcn_layer<CDIM, HDIM, true,  false><<<NB, 256, 0, stream>>>(xb, nb, W1, nullptr, nullptr, hA);
        gcn_layer<HDIM, HDIM, true,  false><<<NB, 256, 0, stream>>>(hA, nb, W2, nullptr, nullptr, hB);
        gcn_layer<HDIM, HDIM, true,  false><<<NB, 256, 0, stream>>>(hB, nb, W3, nullptr, nullptr, hA);
        gcn_layer<HDIM, CDIM, false, true ><<<NB, 256, 0, stream>>>(hA, nb, W4, xb, bid, xout);
    }
}